// Round 1
// baseline (723.958 us; speedup 1.0000x reference)
//
#include <hip/hip_runtime.h>
#include <math.h>

// Problem constants (GlobalSelfAttention): B=8, C=256, CR=32, H=W=64, N=4096
#define B_ 8
#define C_ 256
#define CR_ 32
#define N_ 4096

// ---------------------------------------------------------------------------
// Kernel 1: QKV projection  t[b,o,n] = sum_c Wt[o,c] * x[b,c,n],  o in [0,96)
// Tile: 96 o  x 64 n per block, c staged in chunks of 32 through LDS.
// ---------------------------------------------------------------------------
__global__ __launch_bounds__(256) void qkv_proj(const float* __restrict__ x,
                                                const float* __restrict__ Wt,
                                                float* __restrict__ t) {
  const int b = blockIdx.y;
  const int n0 = blockIdx.x * 64;
  const int tid = threadIdx.x;
  const int tx = tid & 63;   // n within tile
  const int ty = tid >> 6;   // o-group 0..3, thread covers o = ty + 4k
  __shared__ float Xs[32][64];
  __shared__ float Ws[96][32];
  float acc[24];
#pragma unroll
  for (int k = 0; k < 24; ++k) acc[k] = 0.f;
  const float* xb = x + (size_t)b * C_ * N_ + n0;
  for (int c0 = 0; c0 < C_; c0 += 32) {
    __syncthreads();
    for (int idx = tid; idx < 32 * 64; idx += 256) {
      int cc = idx >> 6, nn = idx & 63;
      Xs[cc][nn] = xb[(size_t)(c0 + cc) * N_ + nn];
    }
    for (int idx = tid; idx < 96 * 32; idx += 256) {
      int oo = idx >> 5, cc = idx & 31;
      Ws[oo][cc] = Wt[oo * C_ + c0 + cc];
    }
    __syncthreads();
#pragma unroll 4
    for (int cc = 0; cc < 32; ++cc) {
      float xv = Xs[cc][tx];              // stride-1 across lanes
#pragma unroll
      for (int k = 0; k < 24; ++k)        // Ws read is wave-uniform (broadcast)
        acc[k] += Ws[ty + 4 * k][cc] * xv;
    }
  }
  float* tb = t + (size_t)b * 96 * N_ + n0 + tx;
#pragma unroll
  for (int k = 0; k < 24; ++k) tb[(size_t)(ty + 4 * k) * N_] = acc[k];
}

// ---------------------------------------------------------------------------
// Kernel 2: flash attention over keys i for each query column j.
//   scores[i,j] = sum_c K[c,i]*Q[c,j];  weights = softmax_i;  out[c,j] = V @ w
// Block: one batch b, 128 query columns (BJ=128). Stream key tiles BI=64.
// Online softmax state m,l per j kept in LDS; O accumulators in registers
// (thread owns 4c x 4j of the 32c x 128j output tile).
// ---------------------------------------------------------------------------
__global__ __launch_bounds__(256) void flash_attn(const float* __restrict__ t,
                                                  float* __restrict__ att) {
  const int b = blockIdx.y;
  const int j0g = blockIdx.x * 128;
  const int tid = threadIdx.x;
  const float* K = t + (size_t)b * 96 * N_;  // rows 0..31  = key
  const float* Q = K + 32 * N_;              // rows 32..63 = query
  const float* V = K + 64 * N_;              // rows 64..95 = value

  __shared__ float Qs[32][128];    // 16 KB
  __shared__ float Ks[32][64];     //  8 KB
  __shared__ float Vst[64][32];    //  8 KB (V transposed: [i][c])
  __shared__ float Ps[64][132];    // ~33 KB, padded rows (132*4 B, 16B-aligned)
  __shared__ float m_s[128], l_s[128], alpha_s[128];
  __shared__ float red[2][128];

  for (int idx = tid; idx < 32 * 128; idx += 256) {
    int c = idx >> 7, j = idx & 127;
    Qs[c][j] = Q[(size_t)c * N_ + j0g + j];
  }
  if (tid < 128) { m_s[tid] = -INFINITY; l_s[tid] = 0.f; }

  const int oc0 = (tid >> 5) * 4;   // PV/output mapping: 4 c
  const int oj0 = (tid & 31) * 4;   //                    4 j
  const int si0 = (tid >> 4) * 4;   // S mapping: 4 i
  const int sj0 = (tid & 15) * 8;   //            8 j
  const int jq = tid & 127;         // softmax mapping
  const int half = tid >> 7;

  float acc[4][4];
#pragma unroll
  for (int ci = 0; ci < 4; ++ci)
#pragma unroll
    for (int jj = 0; jj < 4; ++jj) acc[ci][jj] = 0.f;

  for (int i0g = 0; i0g < N_; i0g += 64) {
    __syncthreads();  // protect Ks/Vst/Ps against previous iteration readers
    for (int idx = tid; idx < 32 * 64; idx += 256) {
      int c = idx >> 6, i = idx & 63;
      Ks[c][i] = K[(size_t)c * N_ + i0g + i];
      Vst[i][c] = V[(size_t)c * N_ + i0g + i];
    }
    __syncthreads();

    // ---- S = K_tile^T Q_tile : each thread 4i x 8j, K-dim = 32 ----
    float sacc[4][8];
#pragma unroll
    for (int ii = 0; ii < 4; ++ii)
#pragma unroll
      for (int jj = 0; jj < 8; ++jj) sacc[ii][jj] = 0.f;
#pragma unroll 4
    for (int c = 0; c < 32; ++c) {
      float4 kv = *(const float4*)&Ks[c][si0];
      float4 q0 = *(const float4*)&Qs[c][sj0];
      float4 q1 = *(const float4*)&Qs[c][sj0 + 4];
      const float kk[4] = {kv.x, kv.y, kv.z, kv.w};
      const float qq[8] = {q0.x, q0.y, q0.z, q0.w, q1.x, q1.y, q1.z, q1.w};
#pragma unroll
      for (int ii = 0; ii < 4; ++ii)
#pragma unroll
        for (int jj = 0; jj < 8; ++jj) sacc[ii][jj] += kk[ii] * qq[jj];
    }
#pragma unroll
    for (int ii = 0; ii < 4; ++ii) {
      *(float4*)&Ps[si0 + ii][sj0] =
          make_float4(sacc[ii][0], sacc[ii][1], sacc[ii][2], sacc[ii][3]);
      *(float4*)&Ps[si0 + ii][sj0 + 4] =
          make_float4(sacc[ii][4], sacc[ii][5], sacc[ii][6], sacc[ii][7]);
    }
    __syncthreads();

    // ---- online softmax over i (per column j) ----
    float lmax = -INFINITY;
#pragma unroll 8
    for (int i = half * 32; i < half * 32 + 32; ++i)
      lmax = fmaxf(lmax, Ps[i][jq]);
    red[half][jq] = lmax;
    __syncthreads();
    if (tid < 128) {
      float tmax = fmaxf(red[0][tid], red[1][tid]);
      float mold = m_s[tid];
      float mnew = fmaxf(mold, tmax);
      alpha_s[tid] = __expf(mold - mnew);  // exp(-inf)=0 on first tile
      m_s[tid] = mnew;
    }
    __syncthreads();
    const float mnew = m_s[jq];
    float lsum = 0.f;
#pragma unroll 8
    for (int i = half * 32; i < half * 32 + 32; ++i) {
      float p = __expf(Ps[i][jq] - mnew);
      Ps[i][jq] = p;
      lsum += p;
    }
    red[half][jq] = lsum;
    __syncthreads();
    if (tid < 128) l_s[tid] = l_s[tid] * alpha_s[tid] + red[0][tid] + red[1][tid];

    // ---- O = alpha*O + V_tile @ P ----
    float al[4];
#pragma unroll
    for (int jj = 0; jj < 4; ++jj) al[jj] = alpha_s[oj0 + jj];
#pragma unroll
    for (int ci = 0; ci < 4; ++ci)
#pragma unroll
      for (int jj = 0; jj < 4; ++jj) acc[ci][jj] *= al[jj];
#pragma unroll 4
    for (int i = 0; i < 64; ++i) {
      float4 v = *(const float4*)&Vst[i][oc0];   // broadcast-heavy, cheap
      float4 p = *(const float4*)&Ps[i][oj0];    // stride-1 across lanes
      const float vv[4] = {v.x, v.y, v.z, v.w};
      const float pp[4] = {p.x, p.y, p.z, p.w};
#pragma unroll
      for (int ci = 0; ci < 4; ++ci)
#pragma unroll
        for (int jj = 0; jj < 4; ++jj) acc[ci][jj] += vv[ci] * pp[jj];
    }
  }
  __syncthreads();  // l_s final values
  float invl[4];
#pragma unroll
  for (int jj = 0; jj < 4; ++jj) invl[jj] = 1.f / l_s[oj0 + jj];
  float* ab = att + (size_t)b * CR_ * N_ + j0g;
#pragma unroll
  for (int ci = 0; ci < 4; ++ci) {
    float4 o = make_float4(acc[ci][0] * invl[0], acc[ci][1] * invl[1],
                           acc[ci][2] * invl[2], acc[ci][3] * invl[3]);
    *(float4*)&ab[(size_t)(oc0 + ci) * N_ + oj0] = o;
  }
}

// ---------------------------------------------------------------------------
// Kernel 3: out[b,co,n] = scale * sum_cr Wo[co,cr]*att[b,cr,n] + x[b,co,n]
// ---------------------------------------------------------------------------
__global__ __launch_bounds__(256) void out_proj(const float* __restrict__ att,
                                                const float* __restrict__ Wo,
                                                const float* __restrict__ x,
                                                const float* __restrict__ scale,
                                                float* __restrict__ out) {
  const int b = blockIdx.y;
  const int n0 = blockIdx.x * 256;
  const int tid = threadIdx.x;
  __shared__ float As[32][256];
  __shared__ float WoS[256][32];
  for (int idx = tid; idx < 32 * 256; idx += 256) {
    int cr = idx >> 8, nn = idx & 255;
    As[cr][nn] = att[(size_t)b * CR_ * N_ + (size_t)cr * N_ + n0 + nn];
  }
  for (int idx = tid; idx < 256 * 32; idx += 256) {
    WoS[idx >> 5][idx & 31] = Wo[idx];
  }
  __syncthreads();
  float a[32];
#pragma unroll
  for (int cr = 0; cr < 32; ++cr) a[cr] = As[cr][tid];  // stride-1 per lane
  const float s = scale[0];
  const float* xb = x + (size_t)b * C_ * N_ + n0 + tid;
  float* ob = out + (size_t)b * C_ * N_ + n0 + tid;
  for (int co = 0; co < C_; ++co) {
    float acc2 = 0.f;
#pragma unroll
    for (int cr = 0; cr < 32; ++cr) acc2 += WoS[co][cr] * a[cr];  // broadcast
    ob[(size_t)co * N_] = s * acc2 + xb[(size_t)co * N_];
  }
}

// ---------------------------------------------------------------------------
extern "C" void kernel_launch(void* const* d_in, const int* in_sizes, int n_in,
                              void* d_out, int out_size, void* d_ws,
                              size_t ws_size, hipStream_t stream) {
  const float* x = (const float*)d_in[0];      // [8,256,64,64]
  const float* Wt = (const float*)d_in[1];     // [96,256]
  const float* Wo = (const float*)d_in[2];     // [256,32]
  const float* scale = (const float*)d_in[3];  // [1]
  float* out = (float*)d_out;                  // [8,256,64,64]

  // Workspace layout: t [8,96,4096] fp32 (12.6 MB) | att [8,32,4096] (4.2 MB)
  float* t = (float*)d_ws;
  float* att = t + (size_t)B_ * 96 * N_;

  qkv_proj<<<dim3(N_ / 64, B_), 256, 0, stream>>>(x, Wt, t);
  flash_attn<<<dim3(N_ / 128, B_), 256, 0, stream>>>(t, att);
  out_proj<<<dim3(N_ / 256, B_), 256, 0, stream>>>(att, Wo, x, scale, out);
}

// Round 2
// 244.372 us; speedup vs baseline: 2.9625x; 2.9625x over previous
//
#include <hip/hip_runtime.h>
#include <math.h>

// Problem constants: B=8, C=256, CR=32, N=4096 (=64*64)
#define B_ 8
#define C_ 256
#define CR_ 32
#define N_ 4096

typedef __attribute__((ext_vector_type(8))) short bf16x8;   // MFMA A/B frag (8 bf16)
typedef __attribute__((ext_vector_type(4))) short bf16x4;   // 4 bf16 (8 B)
typedef __attribute__((ext_vector_type(4))) float f32x4;    // MFMA C/D frag

// bf16 round-to-nearest-even (used once per element at the source)
__device__ inline short f2bf(float f) {
  union { float f; unsigned u; } v; v.f = f;
  unsigned r = v.u + 0x7FFFu + ((v.u >> 16) & 1u);
  return (short)(r >> 16);
}
// cheap round (+0.5 ulp) for the hot softmax->P path
__device__ inline short f2bf_r(float f) {
  return (short)((__float_as_uint(f) + 0x8000u) >> 16);
}

// ---------------------------------------------------------------------------
// Kernel 1: QKV projection -> bf16, MFMA-friendly layouts.
//   t_tr[b][n][0..31]  = K[c][n]   (n-major, c contiguous)
//   t_tr[b][n][32..63] = Q[c][n] * log2(e)   (softmax runs in exp2 domain)
//   Vg[b][c][n]        = V[c][n]   (n fastest, for PV A-operand frags)
// Thread (nn 0..63, cbg 0..3) owns n = n0+nn, o = (cbg+4r)*8+e, r=0..2,e=0..7.
// ---------------------------------------------------------------------------
__global__ __launch_bounds__(256, 2) void qkv_proj(const float* __restrict__ x,
                                                   const float* __restrict__ Wt,
                                                   short* __restrict__ t_tr,
                                                   short* __restrict__ Vg) {
  const int b = blockIdx.y, n0 = blockIdx.x * 64;
  const int tid = threadIdx.x;
  const int nn = tid & 63, cbg = tid >> 6;
  __shared__ float Xs[32][64];
  __shared__ float Ws[96][32];
  __shared__ float Vtmp[32][65];
  float acc[3][8];
#pragma unroll
  for (int r = 0; r < 3; ++r)
#pragma unroll
    for (int e = 0; e < 8; ++e) acc[r][e] = 0.f;

  const float* xb = x + (size_t)b * C_ * N_ + n0;
  for (int c0 = 0; c0 < C_; c0 += 32) {
    __syncthreads();
    for (int idx = tid; idx < 2048; idx += 256)
      Xs[idx >> 6][idx & 63] = xb[(size_t)(c0 + (idx >> 6)) * N_ + (idx & 63)];
    for (int idx = tid; idx < 3072; idx += 256)
      Ws[idx >> 5][idx & 31] = Wt[(idx >> 5) * C_ + c0 + (idx & 31)];
    __syncthreads();
#pragma unroll 2
    for (int cc = 0; cc < 32; cc += 4) {
      const float xv0 = Xs[cc + 0][nn], xv1 = Xs[cc + 1][nn];
      const float xv2 = Xs[cc + 2][nn], xv3 = Xs[cc + 3][nn];
#pragma unroll
      for (int r = 0; r < 3; ++r)
#pragma unroll
        for (int e = 0; e < 8; ++e) {
          const float4 w = *(const float4*)&Ws[(cbg + 4 * r) * 8 + e][cc];  // wave-uniform
          acc[r][e] += w.x * xv0 + w.y * xv1 + w.z * xv2 + w.w * xv3;
        }
    }
  }
  // ---- K/Q: pack 8 bf16 and store 16 B (coalesced across nn) ----
  short* trow = t_tr + ((size_t)b * N_ + n0 + nn) * 64;
  {
    bf16x8 pk;
#pragma unroll
    for (int e = 0; e < 8; ++e) pk[e] = f2bf(acc[0][e]);
    *(bf16x8*)(trow + cbg * 8) = pk;  // K section
#pragma unroll
    for (int e = 0; e < 8; ++e) pk[e] = f2bf(acc[1][e] * 1.44269504f);
    *(bf16x8*)(trow + 32 + cbg * 8) = pk;  // Q section (log2e folded)
  }
  // ---- V: LDS transpose to i-fastest, then 16 B coalesced stores ----
#pragma unroll
  for (int e = 0; e < 8; ++e) Vtmp[cbg * 8 + e][nn] = acc[2][e];
  __syncthreads();
  {
    const int c = tid >> 3, ib = tid & 7;
    bf16x8 pv;
#pragma unroll
    for (int e = 0; e < 8; ++e) pv[e] = f2bf(Vtmp[c][ib * 8 + e]);
    *(bf16x8*)(Vg + (size_t)b * CR_ * N_ + (size_t)c * N_ + n0 + ib * 8) = pv;
  }
}

// ---------------------------------------------------------------------------
// Kernel 2: MFMA flash attention. One wave owns 2 j-tiles (32 query cols) and
// streams all 4096 keys in 64-key tiles. No __syncthreads anywhere:
//  - K frag (A: m=i, k=c):  global t_tr[i][c] contiguous 16 B / lane
//  - Q frag (B: k=c, n=j):  global t_tr[j][32+c], loop-invariant, in regs
//  - V frag (A: m=c, k=i):  global Vg[c][i] contiguous 16 B / lane
//  - P:     per-wave LDS, [j][i] bf16, 16B-group XOR swizzle (conflict-free)
//  - softmax state (m,l) per column, replicated across quads via shfl_xor
// ---------------------------------------------------------------------------
__global__ __launch_bounds__(256, 1) void flash_attn(const short* __restrict__ t_tr,
                                                     const short* __restrict__ Vg,
                                                     float* __restrict__ att) {
  const int b = blockIdx.y;
  const int tid = threadIdx.x;
  const int wave = tid >> 6, lane = tid & 63;
  const int col = lane & 15, quad = lane >> 4;
  const int jt0 = blockIdx.x * 8 + wave * 2;  // this wave: j-tiles jt0, jt0+1
  const short* T = t_tr + (size_t)b * N_ * 64;
  const short* V = Vg + (size_t)b * CR_ * N_;

  __shared__ short Pt[4][2][1024];  // [wave][jl][16 cols x 64 i], swizzled
  short* PtW[2] = {&Pt[wave][0][0], &Pt[wave][1][0]};

  const f32x4 z4 = {0.f, 0.f, 0.f, 0.f};
  bf16x8 qf[2];
  qf[0] = *(const bf16x8*)(T + ((jt0 + 0) * 16 + col) * 64 + 32 + quad * 8);
  qf[1] = *(const bf16x8*)(T + ((jt0 + 1) * 16 + col) * 64 + 32 + quad * 8);

  f32x4 acc[2][2] = {{z4, z4}, {z4, z4}};
  float m[2] = {-INFINITY, -INFINITY};
  float l[2] = {0.f, 0.f};

  const short* Kp = T + col * 64 + quad * 8;   // + i*64
  const short* Vp = V + col * N_ + quad * 8;   // + ct*16*N_ + i
  bf16x8 kf[4], vf[4], kfn[4], vfn[4];
#pragma unroll
  for (int it = 0; it < 4; ++it) kf[it] = *(const bf16x8*)(Kp + it * 1024);
#pragma unroll
  for (int ct = 0; ct < 2; ++ct)
#pragma unroll
    for (int ks = 0; ks < 2; ++ks)
      vf[ct * 2 + ks] = *(const bf16x8*)(Vp + ct * 16 * N_ + ks * 32);

  for (int i0 = 0; i0 < N_; i0 += 64) {
    // prefetch next key tile (wraps harmlessly on the last iteration)
    const int inx = (i0 + 64) & (N_ - 1);
#pragma unroll
    for (int it = 0; it < 4; ++it)
      kfn[it] = *(const bf16x8*)(Kp + (inx + it * 16) * 64);
#pragma unroll
    for (int ct = 0; ct < 2; ++ct)
#pragma unroll
      for (int ks = 0; ks < 2; ++ks)
        vfn[ct * 2 + ks] = *(const bf16x8*)(Vp + ct * 16 * N_ + inx + ks * 32);

    // ---- S = K^T Q, online softmax, P -> LDS ----
#pragma unroll
    for (int jl = 0; jl < 2; ++jl) {
      f32x4 s[4];
#pragma unroll
      for (int it = 0; it < 4; ++it)
        s[it] = __builtin_amdgcn_mfma_f32_16x16x32_bf16(kf[it], qf[jl], z4, 0, 0, 0);
      // tile max over the 16 in-lane values, then across quads
      float tm = fmaxf(fmaxf(s[0][0], s[0][1]), fmaxf(s[0][2], s[0][3]));
#pragma unroll
      for (int it = 1; it < 4; ++it)
        tm = fmaxf(tm, fmaxf(fmaxf(s[it][0], s[it][1]), fmaxf(s[it][2], s[it][3])));
      tm = fmaxf(tm, __shfl_xor(tm, 16));
      tm = fmaxf(tm, __shfl_xor(tm, 32));
      const float mn = fmaxf(m[jl], tm);
      const float al = __builtin_amdgcn_exp2f(m[jl] - mn);  // exp2: Q pre-scaled
      m[jl] = mn;
      float ps = 0.f;
      short* P = PtW[jl];
#pragma unroll
      for (int it = 0; it < 4; ++it) {
        const float p0 = __builtin_amdgcn_exp2f(s[it][0] - mn);
        const float p1 = __builtin_amdgcn_exp2f(s[it][1] - mn);
        const float p2 = __builtin_amdgcn_exp2f(s[it][2] - mn);
        const float p3 = __builtin_amdgcn_exp2f(s[it][3] - mn);
        ps += (p0 + p1) + (p2 + p3);
        bf16x4 pk = {f2bf_r(p0), f2bf_r(p1), f2bf_r(p2), f2bf_r(p3)};
        const int g = (it * 2 + (quad >> 1)) ^ (col & 7);  // 16B-group swizzle
        *(bf16x4*)(P + col * 64 + g * 8 + (quad & 1) * 4) = pk;
      }
      ps += __shfl_xor(ps, 16);
      ps += __shfl_xor(ps, 32);
      l[jl] = l[jl] * al + ps;
      acc[jl][0] *= al;
      acc[jl][1] *= al;
    }

    // ---- O += V @ P ----
#pragma unroll
    for (int jl = 0; jl < 2; ++jl) {
      short* P = PtW[jl];
#pragma unroll
      for (int ks = 0; ks < 2; ++ks) {
        const bf16x8 pf =
            *(const bf16x8*)(P + col * 64 + ((ks * 4 + quad) ^ (col & 7)) * 8);
        acc[jl][0] = __builtin_amdgcn_mfma_f32_16x16x32_bf16(vf[0 + ks], pf, acc[jl][0], 0, 0, 0);
        acc[jl][1] = __builtin_amdgcn_mfma_f32_16x16x32_bf16(vf[2 + ks], pf, acc[jl][1], 0, 0, 0);
      }
    }
#pragma unroll
    for (int it = 0; it < 4; ++it) kf[it] = kfn[it];
#pragma unroll
    for (int k = 0; k < 4; ++k) vf[k] = vfn[k];
  }

  // ---- epilogue: divide by l, write att[b][c][j] fp32 ----
#pragma unroll
  for (int jl = 0; jl < 2; ++jl) {
    const float invl = 1.f / l[jl];
#pragma unroll
    for (int ct = 0; ct < 2; ++ct)
#pragma unroll
      for (int r = 0; r < 4; ++r)
        att[(size_t)b * CR_ * N_ + (size_t)(ct * 16 + quad * 4 + r) * N_ +
            (jt0 + jl) * 16 + col] = acc[jl][ct][r] * invl;
  }
}

// ---------------------------------------------------------------------------
// Kernel 3: out[b,co,n] = scale * sum_cr Wo[co,cr]*att[b,cr,n] + x[b,co,n]
// 512 blocks (was 128 -> half the GPU idle). Thread owns 64 co at one n.
// ---------------------------------------------------------------------------
__global__ __launch_bounds__(256, 2) void out_proj(const float* __restrict__ att,
                                                   const float* __restrict__ Wo,
                                                   const float* __restrict__ x,
                                                   const float* __restrict__ scale,
                                                   float* __restrict__ out) {
  const int b = blockIdx.y, n0 = blockIdx.x * 64;
  const int tid = threadIdx.x, nn = tid & 63, cog = tid >> 6;
  __shared__ float As[32][64];
  __shared__ float WoS[256][32];
  for (int idx = tid; idx < 2048; idx += 256)
    As[idx >> 6][idx & 63] =
        att[(size_t)b * CR_ * N_ + (size_t)(idx >> 6) * N_ + n0 + (idx & 63)];
  for (int idx = tid; idx < 8192; idx += 256) ((float*)WoS)[idx] = Wo[idx];
  __syncthreads();
  float a[32];
#pragma unroll
  for (int cr = 0; cr < 32; ++cr) a[cr] = As[cr][nn];
  const float s = scale[0];
  const float* xb = x + (size_t)b * C_ * N_ + n0 + nn;
  float* ob = out + (size_t)b * C_ * N_ + n0 + nn;
  for (int k = 0; k < 64; ++k) {
    const int co = cog * 64 + k;
    const float4* wr = (const float4*)&WoS[co][0];
    float a2 = 0.f;
#pragma unroll
    for (int q = 0; q < 8; ++q) {
      const float4 w = wr[q];
      a2 += w.x * a[q * 4] + w.y * a[q * 4 + 1] + w.z * a[q * 4 + 2] + w.w * a[q * 4 + 3];
    }
    ob[(size_t)co * N_] = s * a2 + xb[(size_t)co * N_];
  }
}

// ---------------------------------------------------------------------------
extern "C" void kernel_launch(void* const* d_in, const int* in_sizes, int n_in,
                              void* d_out, int out_size, void* d_ws,
                              size_t ws_size, hipStream_t stream) {
  const float* x = (const float*)d_in[0];      // [8,256,64,64]
  const float* Wt = (const float*)d_in[1];     // [96,256]
  const float* Wo = (const float*)d_in[2];     // [256,32]
  const float* scale = (const float*)d_in[3];  // [1]
  float* out = (float*)d_out;

  // ws: att fp32 (4.2 MB) | t_tr bf16 [8][4096][64] (4.2 MB) | Vg bf16 (2.1 MB)
  float* att = (float*)d_ws;
  short* t_tr = (short*)(att + (size_t)B_ * CR_ * N_);
  short* Vg = t_tr + (size_t)B_ * N_ * 64;

  qkv_proj<<<dim3(N_ / 64, B_), 256, 0, stream>>>(x, Wt, t_tr, Vg);
  flash_attn<<<dim3(N_ / 128, B_), 256, 0, stream>>>(t_tr, Vg, att);
  out_proj<<<dim3(N_ / 64, B_), 256, 0, stream>>>(att, Wo, x, scale, out);
}

// Round 3
// 211.584 us; speedup vs baseline: 3.4216x; 1.1550x over previous
//
#include <hip/hip_runtime.h>
#include <math.h>

// Problem constants: B=8, C=256, CR=32, N=4096 (=64*64)
#define B_ 8
#define C_ 256
#define CR_ 32
#define N_ 4096

typedef __attribute__((ext_vector_type(8))) short bf16x8;   // MFMA A/B frag
typedef __attribute__((ext_vector_type(4))) short bf16x4;
typedef __attribute__((ext_vector_type(4))) float f32x4;    // MFMA C/D frag

__device__ inline short f2bf(float f) {  // RTNE
  union { float f; unsigned u; } v; v.f = f;
  unsigned r = v.u + 0x7FFFu + ((v.u >> 16) & 1u);
  return (short)(r >> 16);
}
__device__ inline float bf2f(short h) {
  union { unsigned u; float f; } v; v.u = ((unsigned)(unsigned short)h) << 16;
  return v.f;
}
__device__ inline short f2bf_r(float f) {  // cheap round for hot P path
  return (short)((__float_as_uint(f) + 0x8000u) >> 16);
}

// ---------------------------------------------------------------------------
// Kernel 0: weight prep.  WtHi/WtLo = split-bf16 of Wt (log2e folded into Q
// rows 32..63 so softmax runs in exp2 domain).  WoB = bf16(Wo * scale).
// ---------------------------------------------------------------------------
__global__ __launch_bounds__(256) void prep_weights(const float* __restrict__ Wt,
                                                    const float* __restrict__ Wo,
                                                    const float* __restrict__ scale,
                                                    short* __restrict__ WtHi,
                                                    short* __restrict__ WtLo,
                                                    short* __restrict__ WoB) {
  const int blk = blockIdx.x, tid = threadIdx.x;
  if (blk < 96) {
    float v = Wt[blk * C_ + tid];
    if (blk >= 32 && blk < 64) v *= 1.44269504f;  // log2(e) into Q
    const short h = f2bf(v);
    WtHi[blk * C_ + tid] = h;
    WtLo[blk * C_ + tid] = f2bf(v - bf2f(h));
  } else {
    const int idx = (blk - 96) * 256 + tid;  // 32 blocks x 256 = 8192 = 256*32
    WoB[idx] = f2bf(Wo[idx] * scale[0]);
  }
}

// ---------------------------------------------------------------------------
// Kernel 1: QKV projection, pure MFMA, no LDS.
// One x-fragment (8 k-contiguous bf16 at row lane&15) serves as:
//   A-operand for K/Q:  D[n][o] = x^T * Wt^T  -> coalesced t_tr[n][o] stores
//   B-operand for V:    D[c][n] = Wv  * x     -> coalesced Vg[c][n]  stores
// Split-bf16 (hi+lo on both x and W, 3 MFMAs) keeps input error negligible.
// Wave owns one 16-col n-tile; 6 accumulators (4 KQ o-tiles + 2 V c-tiles).
// ---------------------------------------------------------------------------
__global__ __launch_bounds__(256) void qkv_mfma(const float* __restrict__ x,
                                                const short* __restrict__ WtHi,
                                                const short* __restrict__ WtLo,
                                                short* __restrict__ t_tr,
                                                short* __restrict__ Vg) {
  const int b = blockIdx.y;
  const int tid = threadIdx.x;
  const int wave = tid >> 6, lane = tid & 63;
  const int col = lane & 15, quad = lane >> 4;
  const int n0 = (blockIdx.x * 4 + wave) * 16;

  const f32x4 z4 = {0.f, 0.f, 0.f, 0.f};
  f32x4 acc[6] = {z4, z4, z4, z4, z4, z4};  // 0..3 = KQ o-tiles, 4..5 = V

  const float* xb = x + (size_t)b * C_ * N_ + n0 + col;
  for (int c0 = 0; c0 < C_; c0 += 32) {
    // ---- x fragment: 8 coalesced dword loads, split to hi/lo bf16 ----
    bf16x8 xh, xl;
#pragma unroll
    for (int j = 0; j < 8; ++j) {
      const float v = xb[(size_t)(c0 + quad * 8 + j) * N_];
      const short h = f2bf(v);
      xh[j] = h;
      xl[j] = f2bf(v - bf2f(h));
    }
    // ---- W fragments from L2 (16B each) ----
#pragma unroll
    for (int ot = 0; ot < 4; ++ot) {  // K/Q: B-operand = Wt rows 0..63
      const int off = (ot * 16 + col) * C_ + c0 + quad * 8;
      const bf16x8 bh = *(const bf16x8*)(WtHi + off);
      const bf16x8 bl = *(const bf16x8*)(WtLo + off);
      acc[ot] = __builtin_amdgcn_mfma_f32_16x16x32_bf16(xh, bh, acc[ot], 0, 0, 0);
      acc[ot] = __builtin_amdgcn_mfma_f32_16x16x32_bf16(xl, bh, acc[ot], 0, 0, 0);
      acc[ot] = __builtin_amdgcn_mfma_f32_16x16x32_bf16(xh, bl, acc[ot], 0, 0, 0);
    }
#pragma unroll
    for (int ct = 0; ct < 2; ++ct) {  // V: A-operand = Wt rows 64..95
      const int off = ((64 + ct * 16) + col) * C_ + c0 + quad * 8;
      const bf16x8 ah = *(const bf16x8*)(WtHi + off);
      const bf16x8 al = *(const bf16x8*)(WtLo + off);
      acc[4 + ct] = __builtin_amdgcn_mfma_f32_16x16x32_bf16(ah, xh, acc[4 + ct], 0, 0, 0);
      acc[4 + ct] = __builtin_amdgcn_mfma_f32_16x16x32_bf16(ah, xl, acc[4 + ct], 0, 0, 0);
      acc[4 + ct] = __builtin_amdgcn_mfma_f32_16x16x32_bf16(al, xh, acc[4 + ct], 0, 0, 0);
    }
  }
  // ---- K/Q epilogue: D[n][o], row=quad*4+r -> n, col(lane&15) -> o ----
#pragma unroll
  for (int ot = 0; ot < 4; ++ot)
#pragma unroll
    for (int r = 0; r < 4; ++r)
      t_tr[((size_t)b * N_ + n0 + quad * 4 + r) * 64 + ot * 16 + col] =
          f2bf(acc[ot][r]);
  // ---- V epilogue: D[c][n], row -> c, col -> n ----
#pragma unroll
  for (int ct = 0; ct < 2; ++ct)
#pragma unroll
    for (int r = 0; r < 4; ++r)
      Vg[(size_t)b * CR_ * N_ + (size_t)(ct * 16 + quad * 4 + r) * N_ + n0 + col] =
          f2bf(acc[4 + ct][r]);
}

// ---------------------------------------------------------------------------
// Kernel 2: MFMA flash attention, split-K across the 4 waves of a block.
// Block = 128 query cols x one batch.  Wave w streams i-tiles == w (mod 4)
// (16 tiles of 64 keys) with private online-softmax state (m,l per j) and a
// private O accumulator -> ZERO barriers in the main loop, each block reads
// K and V exactly once.  Flash-decode merge through LDS at the end; output
// written as attT[n][cr] bf16 (the B-operand layout out_proj needs).
// ---------------------------------------------------------------------------
__global__ __launch_bounds__(256, 1) void flash_attn(const short* __restrict__ t_tr,
                                                     const short* __restrict__ Vg,
                                                     short* __restrict__ attT) {
  const int b = blockIdx.y;
  const int j0 = blockIdx.x * 128;
  const int tid = threadIdx.x;
  const int wave = tid >> 6, lane = tid & 63;
  const int col = lane & 15, quad = lane >> 4;
  const short* T = t_tr + (size_t)b * N_ * 64;
  const short* V = Vg + (size_t)b * CR_ * N_;

  __shared__ short P[4][8192];       // per-wave [j(128)][i(64)] bf16, swizzled
  __shared__ float Oacc[128][33];    // merge accumulator [j][c], padded
  __shared__ float mlL[2][4][128];   // per-wave m,l per j

  for (int idx = tid; idx < 128 * 33; idx += 256) (&Oacc[0][0])[idx] = 0.f;
  short* Pw = P[wave];

  const f32x4 z4 = {0.f, 0.f, 0.f, 0.f};
  bf16x8 qf[8];  // loop-invariant Q fragments (8 j-tiles)
#pragma unroll
  for (int jt = 0; jt < 8; ++jt)
    qf[jt] = *(const bf16x8*)(T + ((size_t)(j0 + jt * 16 + col)) * 64 + 32 + quad * 8);

  f32x4 acc[2][8];
#pragma unroll
  for (int ct = 0; ct < 2; ++ct)
#pragma unroll
    for (int jt = 0; jt < 8; ++jt) acc[ct][jt] = z4;
  float m[8], l[8];
#pragma unroll
  for (int jt = 0; jt < 8; ++jt) { m[jt] = -INFINITY; l[jt] = 0.f; }

  int i0 = wave * 64;
  bf16x8 kf[4], vf[4], kfn[4], vfn[4];
#pragma unroll
  for (int it = 0; it < 4; ++it)
    kf[it] = *(const bf16x8*)(T + (size_t)(i0 + it * 16 + col) * 64 + quad * 8);
#pragma unroll
  for (int ct = 0; ct < 2; ++ct)
#pragma unroll
    for (int ks = 0; ks < 2; ++ks)
      vf[ct * 2 + ks] =
          *(const bf16x8*)(V + (size_t)(ct * 16 + col) * N_ + i0 + ks * 32 + quad * 8);

  for (int iter = 0; iter < 16; ++iter) {
    const int inx = (i0 + 256) & (N_ - 1);  // this wave's next tile
#pragma unroll
    for (int it = 0; it < 4; ++it)
      kfn[it] = *(const bf16x8*)(T + (size_t)(inx + it * 16 + col) * 64 + quad * 8);
#pragma unroll
    for (int ct = 0; ct < 2; ++ct)
#pragma unroll
      for (int ks = 0; ks < 2; ++ks)
        vfn[ct * 2 + ks] =
            *(const bf16x8*)(V + (size_t)(ct * 16 + col) * N_ + inx + ks * 32 + quad * 8);

#pragma unroll
    for (int jt = 0; jt < 8; ++jt) {
      // ---- S tile (64i x 16j) ----
      f32x4 s[4];
#pragma unroll
      for (int it = 0; it < 4; ++it)
        s[it] = __builtin_amdgcn_mfma_f32_16x16x32_bf16(kf[it], qf[jt], z4, 0, 0, 0);
      // ---- online softmax (exp2 domain; Q pre-scaled by log2e) ----
      float tm = fmaxf(fmaxf(s[0][0], s[0][1]), fmaxf(s[0][2], s[0][3]));
#pragma unroll
      for (int it = 1; it < 4; ++it)
        tm = fmaxf(tm, fmaxf(fmaxf(s[it][0], s[it][1]), fmaxf(s[it][2], s[it][3])));
      tm = fmaxf(tm, __shfl_xor(tm, 16));
      tm = fmaxf(tm, __shfl_xor(tm, 32));
      const float mn = fmaxf(m[jt], tm);
      const float al = __builtin_amdgcn_exp2f(m[jt] - mn);
      m[jt] = mn;
      float ps = 0.f;
#pragma unroll
      for (int it = 0; it < 4; ++it) {
        const float p0 = __builtin_amdgcn_exp2f(s[it][0] - mn);
        const float p1 = __builtin_amdgcn_exp2f(s[it][1] - mn);
        const float p2 = __builtin_amdgcn_exp2f(s[it][2] - mn);
        const float p3 = __builtin_amdgcn_exp2f(s[it][3] - mn);
        ps += (p0 + p1) + (p2 + p3);
        bf16x4 pk = {f2bf_r(p0), f2bf_r(p1), f2bf_r(p2), f2bf_r(p3)};
        const int g = it * 2 + (quad >> 1);  // 16B-group + XOR swizzle
        *(bf16x4*)(Pw + (jt * 16 + col) * 64 + ((g ^ (col & 7)) * 8) + (quad & 1) * 4) = pk;
      }
      ps += __shfl_xor(ps, 16);
      ps += __shfl_xor(ps, 32);
      l[jt] = l[jt] * al + ps;
      acc[0][jt] *= al;
      acc[1][jt] *= al;
      // ---- O += V @ P ----
#pragma unroll
      for (int ks = 0; ks < 2; ++ks) {
        const bf16x8 pf =
            *(const bf16x8*)(Pw + (jt * 16 + col) * 64 + (((ks * 4 + quad) ^ (col & 7)) * 8));
        acc[0][jt] = __builtin_amdgcn_mfma_f32_16x16x32_bf16(vf[0 + ks], pf, acc[0][jt], 0, 0, 0);
        acc[1][jt] = __builtin_amdgcn_mfma_f32_16x16x32_bf16(vf[2 + ks], pf, acc[1][jt], 0, 0, 0);
      }
    }
    i0 = inx;
#pragma unroll
    for (int it = 0; it < 4; ++it) kf[it] = kfn[it];
#pragma unroll
    for (int k = 0; k < 4; ++k) vf[k] = vfn[k];
  }

  // ---- flash-decode merge across the 4 waves ----
  if (quad == 0) {
#pragma unroll
    for (int jt = 0; jt < 8; ++jt) {
      mlL[0][wave][jt * 16 + col] = m[jt];
      mlL[1][wave][jt * 16 + col] = l[jt];
    }
  }
  __syncthreads();
#pragma unroll
  for (int jt = 0; jt < 8; ++jt) {
    const int j = jt * 16 + col;
    float mM = mlL[0][0][j];
    mM = fmaxf(mM, mlL[0][1][j]);
    mM = fmaxf(mM, mlL[0][2][j]);
    mM = fmaxf(mM, mlL[0][3][j]);
    float denom = 0.f;
#pragma unroll
    for (int w = 0; w < 4; ++w)
      denom += mlL[1][w][j] * __builtin_amdgcn_exp2f(mlL[0][w][j] - mM);
    const float coef = __builtin_amdgcn_exp2f(m[jt] - mM) / denom;
#pragma unroll
    for (int ct = 0; ct < 2; ++ct)
#pragma unroll
      for (int r = 0; r < 4; ++r)
        atomicAdd(&Oacc[j][ct * 16 + quad * 4 + r], acc[ct][jt][r] * coef);
  }
  __syncthreads();
  // ---- write attT[b][j][cr] bf16 (B-operand layout for out_proj) ----
  {
    const int j = tid >> 1, cg = tid & 1;
    bf16x8 o0, o1;
#pragma unroll
    for (int k = 0; k < 8; ++k) {
      o0[k] = f2bf(Oacc[j][cg * 16 + k]);
      o1[k] = f2bf(Oacc[j][cg * 16 + 8 + k]);
    }
    short* dst = attT + ((size_t)b * N_ + j0 + j) * 32 + cg * 16;
    *(bf16x8*)dst = o0;
    *(bf16x8*)(dst + 8) = o1;
  }
}

// ---------------------------------------------------------------------------
// Kernel 3: out[b,co,n] = WoB(=Wo*scale) @ attT + x.   k=32 single MFMA.
// Wave owns one n-tile (16 cols) x all 16 co-tiles.
// ---------------------------------------------------------------------------
__global__ __launch_bounds__(256) void out_proj(const short* __restrict__ attT,
                                                const short* __restrict__ WoB,
                                                const float* __restrict__ x,
                                                float* __restrict__ out) {
  const int b = blockIdx.y;
  const int tid = threadIdx.x;
  const int wave = tid >> 6, lane = tid & 63;
  const int col = lane & 15, quad = lane >> 4;
  const int n0 = (blockIdx.x * 4 + wave) * 16;

  const f32x4 z4 = {0.f, 0.f, 0.f, 0.f};
  const bf16x8 bf = *(const bf16x8*)(attT + ((size_t)b * N_ + n0 + col) * 32 + quad * 8);
  const float* xb = x + (size_t)b * C_ * N_;
  float* ob = out + (size_t)b * C_ * N_;
#pragma unroll
  for (int ct = 0; ct < 16; ++ct) {
    const bf16x8 af = *(const bf16x8*)(WoB + (ct * 16 + col) * 32 + quad * 8);
    const f32x4 a = __builtin_amdgcn_mfma_f32_16x16x32_bf16(af, bf, z4, 0, 0, 0);
#pragma unroll
    for (int r = 0; r < 4; ++r) {
      const size_t idx = (size_t)(ct * 16 + quad * 4 + r) * N_ + n0 + col;
      ob[idx] = a[r] + xb[idx];
    }
  }
}

// ---------------------------------------------------------------------------
extern "C" void kernel_launch(void* const* d_in, const int* in_sizes, int n_in,
                              void* d_out, int out_size, void* d_ws,
                              size_t ws_size, hipStream_t stream) {
  const float* x = (const float*)d_in[0];      // [8,256,64,64]
  const float* Wt = (const float*)d_in[1];     // [96,256]
  const float* Wo = (const float*)d_in[2];     // [256,32]
  const float* scale = (const float*)d_in[3];  // [1]
  float* out = (float*)d_out;

  // ws (all bf16/short): t_tr[8][4096][64] | Vg[8][32][4096] | attT[8][4096][32]
  //                      | WtHi[96][256] | WtLo[96][256] | WoB[256][32]
  short* t_tr = (short*)d_ws;
  short* Vg = t_tr + (size_t)B_ * N_ * 64;
  short* attT = Vg + (size_t)B_ * CR_ * N_;
  short* WtHi = attT + (size_t)B_ * N_ * CR_;
  short* WtLo = WtHi + 96 * C_;
  short* WoB = WtLo + 96 * C_;

  prep_weights<<<dim3(128), 256, 0, stream>>>(Wt, Wo, scale, WtHi, WtLo, WoB);
  qkv_mfma<<<dim3(64, B_), 256, 0, stream>>>(x, WtHi, WtLo, t_tr, Vg);
  flash_attn<<<dim3(32, B_), 256, 0, stream>>>(t_tr, Vg, attT);
  out_proj<<<dim3(64, B_), 256, 0, stream>>>(attT, WoB, x, out);
}

// Round 4
// 197.929 us; speedup vs baseline: 3.6577x; 1.0690x over previous
//
#include <hip/hip_runtime.h>
#include <math.h>

// Problem constants: B=8, C=256, CR=32, N=4096 (=64*64)
#define B_ 8
#define C_ 256
#define CR_ 32
#define N_ 4096

typedef __attribute__((ext_vector_type(8))) short bf16x8;   // MFMA A/B frag
typedef __attribute__((ext_vector_type(4))) short bf16x4;
typedef __attribute__((ext_vector_type(4))) float f32x4;    // MFMA C/D frag

__device__ inline short f2bf(float f) {  // RTNE
  union { float f; unsigned u; } v; v.f = f;
  unsigned r = v.u + 0x7FFFu + ((v.u >> 16) & 1u);
  return (short)(r >> 16);
}
__device__ inline float bf2f(short h) {
  union { unsigned u; float f; } v; v.u = ((unsigned)(unsigned short)h) << 16;
  return v.f;
}
__device__ inline short f2bf_r(float f) {  // cheap round for hot P path
  return (short)((__float_as_uint(f) + 0x8000u) >> 16);
}

// ---------------------------------------------------------------------------
// Kernel 0: weight prep.  WtHi/WtLo = split-bf16 of Wt (log2e folded into Q
// rows 32..63 so softmax runs in exp2 domain).  WoB = bf16(Wo * scale).
// ---------------------------------------------------------------------------
__global__ __launch_bounds__(256) void prep_weights(const float* __restrict__ Wt,
                                                    const float* __restrict__ Wo,
                                                    const float* __restrict__ scale,
                                                    short* __restrict__ WtHi,
                                                    short* __restrict__ WtLo,
                                                    short* __restrict__ WoB) {
  const int blk = blockIdx.x, tid = threadIdx.x;
  if (blk < 96) {
    float v = Wt[blk * C_ + tid];
    if (blk >= 32 && blk < 64) v *= 1.44269504f;  // log2(e) into Q
    const short h = f2bf(v);
    WtHi[blk * C_ + tid] = h;
    WtLo[blk * C_ + tid] = f2bf(v - bf2f(h));
  } else {
    const int idx = (blk - 96) * 256 + tid;
    WoB[idx] = f2bf(Wo[idx] * scale[0]);
  }
}

// ---------------------------------------------------------------------------
// Kernel 1: QKV projection, pure MFMA, no LDS, x prefetched one chunk ahead.
//   t_tr[b][n][0..31]=K, [32..63]=Q*log2e (bf16);  Vg[b][c][n]=V (bf16)
// ---------------------------------------------------------------------------
__global__ __launch_bounds__(256) void qkv_mfma(const float* __restrict__ x,
                                                const short* __restrict__ WtHi,
                                                const short* __restrict__ WtLo,
                                                short* __restrict__ t_tr,
                                                short* __restrict__ Vg) {
  const int b = blockIdx.y;
  const int tid = threadIdx.x;
  const int wave = tid >> 6, lane = tid & 63;
  const int col = lane & 15, quad = lane >> 4;
  const int n0 = (blockIdx.x * 4 + wave) * 16;

  const f32x4 z4 = {0.f, 0.f, 0.f, 0.f};
  f32x4 acc[6] = {z4, z4, z4, z4, z4, z4};  // 0..3 = KQ o-tiles, 4..5 = V

  const float* xb = x + (size_t)b * C_ * N_ + n0 + col;
  float xcur[8], xnxt[8];
#pragma unroll
  for (int j = 0; j < 8; ++j) xcur[j] = xb[(size_t)(quad * 8 + j) * N_];

  for (int c0 = 0; c0 < C_; c0 += 32) {
    if (c0 < C_ - 32) {
#pragma unroll
      for (int j = 0; j < 8; ++j)
        xnxt[j] = xb[(size_t)(c0 + 32 + quad * 8 + j) * N_];
    }
    bf16x8 xh, xl;
#pragma unroll
    for (int j = 0; j < 8; ++j) {
      const short h = f2bf(xcur[j]);
      xh[j] = h;
      xl[j] = f2bf(xcur[j] - bf2f(h));
    }
#pragma unroll
    for (int ot = 0; ot < 4; ++ot) {  // K/Q: B-operand = Wt rows 0..63
      const int off = (ot * 16 + col) * C_ + c0 + quad * 8;
      const bf16x8 bh = *(const bf16x8*)(WtHi + off);
      const bf16x8 bl = *(const bf16x8*)(WtLo + off);
      acc[ot] = __builtin_amdgcn_mfma_f32_16x16x32_bf16(xh, bh, acc[ot], 0, 0, 0);
      acc[ot] = __builtin_amdgcn_mfma_f32_16x16x32_bf16(xl, bh, acc[ot], 0, 0, 0);
      acc[ot] = __builtin_amdgcn_mfma_f32_16x16x32_bf16(xh, bl, acc[ot], 0, 0, 0);
    }
#pragma unroll
    for (int ct = 0; ct < 2; ++ct) {  // V: A-operand = Wt rows 64..95
      const int off = ((64 + ct * 16) + col) * C_ + c0 + quad * 8;
      const bf16x8 ah = *(const bf16x8*)(WtHi + off);
      const bf16x8 al = *(const bf16x8*)(WtLo + off);
      acc[4 + ct] = __builtin_amdgcn_mfma_f32_16x16x32_bf16(ah, xh, acc[4 + ct], 0, 0, 0);
      acc[4 + ct] = __builtin_amdgcn_mfma_f32_16x16x32_bf16(ah, xl, acc[4 + ct], 0, 0, 0);
      acc[4 + ct] = __builtin_amdgcn_mfma_f32_16x16x32_bf16(al, xh, acc[4 + ct], 0, 0, 0);
    }
#pragma unroll
    for (int j = 0; j < 8; ++j) xcur[j] = xnxt[j];
  }
  // K/Q epilogue: D[n][o]
#pragma unroll
  for (int ot = 0; ot < 4; ++ot)
#pragma unroll
    for (int r = 0; r < 4; ++r)
      t_tr[((size_t)b * N_ + n0 + quad * 4 + r) * 64 + ot * 16 + col] =
          f2bf(acc[ot][r]);
  // V epilogue: D[c][n]
#pragma unroll
  for (int ct = 0; ct < 2; ++ct)
#pragma unroll
    for (int r = 0; r < 4; ++r)
      Vg[(size_t)b * CR_ * N_ + (size_t)(ct * 16 + quad * 4 + r) * N_ + n0 + col] =
          f2bf(acc[4 + ct][r]);
}

// ---------------------------------------------------------------------------
// Kernel 2: MFMA flash attention, NO max subtraction (scores bounded: p=2^s
// stays inside f32/bf16 exponent range; softmax is shift-invariant so the
// result is identical).  No cross-lane ops in the main loop at all.
// Grid (64 j-blocks, 2 kv-halves, 8 b) = 1024 blocks; 4 waves split the
// half's 2048 keys.  l = sum p comes from an extra PV MFMA with a constant
// ones-row A operand.  Partials (unnormalized O, l) -> global; out_proj
// merges the two halves and normalizes.
// ---------------------------------------------------------------------------
__global__ __launch_bounds__(256, 3) void flash_attn(const short* __restrict__ t_tr,
                                                     const short* __restrict__ Vg,
                                                     float* __restrict__ OPart,
                                                     float* __restrict__ LPart) {
  const int b = blockIdx.z, h = blockIdx.y;
  const int j0 = blockIdx.x * 64;
  const int tid = threadIdx.x;
  const int wave = tid >> 6, lane = tid & 63;
  const int col = lane & 15, quad = lane >> 4;
  const short* T = t_tr + (size_t)b * N_ * 64;
  const short* V = Vg + (size_t)b * CR_ * N_;

  __shared__ short P[4][4096];     // 32 KB: per-wave [j(64)][i(64)], swizzled
  __shared__ float Oacc[64][36];   // 9.2 KB merge accumulator [j][c]
  __shared__ float Lacc[64];
  for (int idx = tid; idx < 64 * 36; idx += 256) (&Oacc[0][0])[idx] = 0.f;
  if (tid < 64) Lacc[tid] = 0.f;
  __syncthreads();
  short* Pw = P[wave];

  const f32x4 z4 = {0.f, 0.f, 0.f, 0.f};
  bf16x8 qf[4];
#pragma unroll
  for (int jt = 0; jt < 4; ++jt)
    qf[jt] = *(const bf16x8*)(T + (size_t)(j0 + jt * 16 + col) * 64 + 32 + quad * 8);

  bf16x8 onesA;  // A-operand with row c'=0 all ones -> D row 0 = column sums
  {
    const short one = (col == 0) ? (short)0x3F80 : (short)0;
#pragma unroll
    for (int e = 0; e < 8; ++e) onesA[e] = one;
  }

  f32x4 acc[4][2], accl[4];
#pragma unroll
  for (int jt = 0; jt < 4; ++jt) {
    acc[jt][0] = z4; acc[jt][1] = z4; accl[jt] = z4;
  }

  const int ibase = h * 2048;
  int i0 = ibase + wave * 64;
  bf16x8 kf[4], kfn[4];
#pragma unroll
  for (int it = 0; it < 4; ++it)
    kf[it] = *(const bf16x8*)(T + (size_t)(i0 + it * 16 + col) * 64 + quad * 8);

  for (int iter = 0; iter < 8; ++iter) {
    const int inx = ibase + ((iter + 1) & 7) * 256 + wave * 64;
#pragma unroll
    for (int it = 0; it < 4; ++it)
      kfn[it] = *(const bf16x8*)(T + (size_t)(inx + it * 16 + col) * 64 + quad * 8);
    bf16x8 vf[4];
#pragma unroll
    for (int ct = 0; ct < 2; ++ct)
#pragma unroll
      for (int ks = 0; ks < 2; ++ks)
        vf[ct * 2 + ks] =
            *(const bf16x8*)(V + (size_t)(ct * 16 + col) * N_ + i0 + ks * 32 + quad * 8);

#pragma unroll
    for (int jt = 0; jt < 4; ++jt) {
      f32x4 s[4];
#pragma unroll
      for (int it = 0; it < 4; ++it)
        s[it] = __builtin_amdgcn_mfma_f32_16x16x32_bf16(kf[it], qf[jt], z4, 0, 0, 0);
      // p = exp2(s) raw (no max): pack to bf16, swizzled LDS
#pragma unroll
      for (int it = 0; it < 4; ++it) {
        const float p0 = __builtin_amdgcn_exp2f(s[it][0]);
        const float p1 = __builtin_amdgcn_exp2f(s[it][1]);
        const float p2 = __builtin_amdgcn_exp2f(s[it][2]);
        const float p3 = __builtin_amdgcn_exp2f(s[it][3]);
        bf16x4 pk = {f2bf_r(p0), f2bf_r(p1), f2bf_r(p2), f2bf_r(p3)};
        const int g = it * 2 + (quad >> 1);
        *(bf16x4*)(Pw + (jt * 16 + col) * 64 + ((g ^ (col & 7)) * 8) + (quad & 1) * 4) = pk;
      }
      // O += V @ P ; l += ones @ P
#pragma unroll
      for (int ks = 0; ks < 2; ++ks) {
        const bf16x8 pf =
            *(const bf16x8*)(Pw + (jt * 16 + col) * 64 + (((ks * 4 + quad) ^ (col & 7)) * 8));
        acc[jt][0] = __builtin_amdgcn_mfma_f32_16x16x32_bf16(vf[0 + ks], pf, acc[jt][0], 0, 0, 0);
        acc[jt][1] = __builtin_amdgcn_mfma_f32_16x16x32_bf16(vf[2 + ks], pf, acc[jt][1], 0, 0, 0);
        accl[jt]   = __builtin_amdgcn_mfma_f32_16x16x32_bf16(onesA, pf, accl[jt], 0, 0, 0);
      }
    }
    i0 = inx;
#pragma unroll
    for (int it = 0; it < 4; ++it) kf[it] = kfn[it];
  }

  // ---- block merge (plain sums; no m to reconcile) ----
#pragma unroll
  for (int jt = 0; jt < 4; ++jt) {
    const int j = jt * 16 + col;
#pragma unroll
    for (int ct = 0; ct < 2; ++ct)
#pragma unroll
      for (int r = 0; r < 4; ++r)
        atomicAdd(&Oacc[j][ct * 16 + quad * 4 + r], acc[jt][ct][r]);
    if (quad == 0) atomicAdd(&Lacc[j], accl[jt][0]);
  }
  __syncthreads();
  // ---- write partials: OPart[b][h][jblk][j][c] f32, LPart likewise ----
  float* OP = OPart + ((((size_t)b * 2 + h) * 64 + blockIdx.x) * 64) * 32;
  for (int idx = tid; idx < 512; idx += 256) {  // 512 float4s
    const int j = idx >> 3, cq = idx & 7;
    *(float4*)(OP + j * 32 + cq * 4) = *(const float4*)&Oacc[j][cq * 4];
  }
  if (tid < 64)
    LPart[(((size_t)b * 2 + h) * 64 + blockIdx.x) * 64 + tid] = Lacc[tid];
}

// ---------------------------------------------------------------------------
// Kernel 3: merge the 2 KV-half partials, normalize, out-proj, residual.
// Grid (64 n-blocks, 2 co-halves, 8 b) = 1024 blocks.
// out[b,co,n] = WoB @ ((O0+O1)/(l0+l1)) + x
// ---------------------------------------------------------------------------
__global__ __launch_bounds__(256) void out_proj(const float* __restrict__ OPart,
                                                const float* __restrict__ LPart,
                                                const short* __restrict__ WoB,
                                                const float* __restrict__ x,
                                                float* __restrict__ out) {
  const int b = blockIdx.z, chalf = blockIdx.y;
  const int tid = threadIdx.x;
  const int wave = tid >> 6, lane = tid & 63;
  const int col = lane & 15, quad = lane >> 4;
  const int jblk = blockIdx.x;
  const int jloc = wave * 16 + col;          // j within the 64-block
  const int n0 = jblk * 64 + wave * 16;      // global n of this wave's tile

  const size_t p0 = (((size_t)b * 2 + 0) * 64 + jblk) * 64 + jloc;
  const size_t p1 = (((size_t)b * 2 + 1) * 64 + jblk) * 64 + jloc;
  const float4 o0a = *(const float4*)(OPart + p0 * 32 + quad * 8);
  const float4 o0b = *(const float4*)(OPart + p0 * 32 + quad * 8 + 4);
  const float4 o1a = *(const float4*)(OPart + p1 * 32 + quad * 8);
  const float4 o1b = *(const float4*)(OPart + p1 * 32 + quad * 8 + 4);
  const float linv = 1.f / (LPart[p0] + LPart[p1]);

  bf16x8 bf;
  bf[0] = f2bf((o0a.x + o1a.x) * linv);
  bf[1] = f2bf((o0a.y + o1a.y) * linv);
  bf[2] = f2bf((o0a.z + o1a.z) * linv);
  bf[3] = f2bf((o0a.w + o1a.w) * linv);
  bf[4] = f2bf((o0b.x + o1b.x) * linv);
  bf[5] = f2bf((o0b.y + o1b.y) * linv);
  bf[6] = f2bf((o0b.z + o1b.z) * linv);
  bf[7] = f2bf((o0b.w + o1b.w) * linv);

  const f32x4 z4 = {0.f, 0.f, 0.f, 0.f};
  const float* xb = x + (size_t)b * C_ * N_;
  float* ob = out + (size_t)b * C_ * N_;
#pragma unroll
  for (int ct = 0; ct < 8; ++ct) {
    const int ctg = chalf * 8 + ct;
    const bf16x8 af = *(const bf16x8*)(WoB + (ctg * 16 + col) * 32 + quad * 8);
    const f32x4 a = __builtin_amdgcn_mfma_f32_16x16x32_bf16(af, bf, z4, 0, 0, 0);
#pragma unroll
    for (int r = 0; r < 4; ++r) {
      const size_t idx = (size_t)(ctg * 16 + quad * 4 + r) * N_ + n0 + col;
      ob[idx] = a[r] + xb[idx];
    }
  }
}

// ---------------------------------------------------------------------------
extern "C" void kernel_launch(void* const* d_in, const int* in_sizes, int n_in,
                              void* d_out, int out_size, void* d_ws,
                              size_t ws_size, hipStream_t stream) {
  const float* x = (const float*)d_in[0];      // [8,256,64,64]
  const float* Wt = (const float*)d_in[1];     // [96,256]
  const float* Wo = (const float*)d_in[2];     // [256,32]
  const float* scale = (const float*)d_in[3];  // [1]
  float* out = (float*)d_out;

  // ws: OPart f32 [8][2][64][64][32] (8 MB) | LPart f32 (256 KB)
  //   | t_tr bf16 [8][4096][64] (4 MB) | Vg bf16 (2 MB) | WtHi/WtLo | WoB
  float* OPart = (float*)d_ws;
  float* LPart = OPart + (size_t)B_ * 2 * 64 * 64 * 32;
  short* t_tr = (short*)(LPart + (size_t)B_ * 2 * 64 * 64);
  short* Vg = t_tr + (size_t)B_ * N_ * 64;
  short* WtHi = Vg + (size_t)B_ * CR_ * N_;
  short* WtLo = WtHi + 96 * C_;
  short* WoB = WtLo + 96 * C_;

  prep_weights<<<dim3(128), 256, 0, stream>>>(Wt, Wo, scale, WtHi, WtLo, WoB);
  qkv_mfma<<<dim3(64, B_), 256, 0, stream>>>(x, WtHi, WtLo, t_tr, Vg);
  flash_attn<<<dim3(64, 2, B_), 256, 0, stream>>>(t_tr, Vg, OPart, LPart);
  out_proj<<<dim3(64, 2, B_), 256, 0, stream>>>(OPart, LPart, WoB, x, out);
}

// Round 5
// 192.236 us; speedup vs baseline: 3.7660x; 1.0296x over previous
//
#include <hip/hip_runtime.h>
#include <math.h>

// Problem constants: B=8, C=256, CR=32, N=4096 (=64*64)
#define B_ 8
#define C_ 256
#define CR_ 32
#define N_ 4096

typedef __attribute__((ext_vector_type(8))) short bf16x8;   // MFMA A/B frag
typedef __attribute__((ext_vector_type(4))) short bf16x4;
typedef __attribute__((ext_vector_type(4))) float f32x4;    // MFMA C/D frag

__device__ inline short f2bf(float f) {  // RTNE
  union { float f; unsigned u; } v; v.f = f;
  unsigned r = v.u + 0x7FFFu + ((v.u >> 16) & 1u);
  return (short)(r >> 16);
}
__device__ inline float bf2f(short h) {
  union { unsigned u; float f; } v; v.u = ((unsigned)(unsigned short)h) << 16;
  return v.f;
}
__device__ inline short f2bf_r(float f) {  // cheap round for hot paths
  return (short)((__float_as_uint(f) + 0x8000u) >> 16);
}

// ---------------------------------------------------------------------------
// Kernel 0: weight prep.  WtHi/WtLo = split-bf16 of Wt (log2e folded into Q
// rows 32..63 so softmax runs in exp2 domain).  WoB = bf16(Wo * scale).
// ---------------------------------------------------------------------------
__global__ __launch_bounds__(256) void prep_weights(const float* __restrict__ Wt,
                                                    const float* __restrict__ Wo,
                                                    const float* __restrict__ scale,
                                                    short* __restrict__ WtHi,
                                                    short* __restrict__ WtLo,
                                                    short* __restrict__ WoB) {
  const int blk = blockIdx.x, tid = threadIdx.x;
  if (blk < 96) {
    float v = Wt[blk * C_ + tid];
    if (blk >= 32 && blk < 64) v *= 1.44269504f;  // log2(e) into Q
    const short h = f2bf(v);
    WtHi[blk * C_ + tid] = h;
    WtLo[blk * C_ + tid] = f2bf(v - bf2f(h));
  } else {
    const int idx = (blk - 96) * 256 + tid;
    WoB[idx] = f2bf(Wo[idx] * scale[0]);
  }
}

// ---------------------------------------------------------------------------
// Kernel 1: QKV projection, pure MFMA, no LDS, x prefetched one chunk ahead.
//   t_tr[b][n][0..31]=K, [32..63]=Q*log2e (bf16);  Vg[b][c][n]=V (bf16)
// x hi/lo split uses truncation for hi (1 op) — lo corrects it exactly.
// ---------------------------------------------------------------------------
__global__ __launch_bounds__(256) void qkv_mfma(const float* __restrict__ x,
                                                const short* __restrict__ WtHi,
                                                const short* __restrict__ WtLo,
                                                short* __restrict__ t_tr,
                                                short* __restrict__ Vg) {
  const int b = blockIdx.y;
  const int tid = threadIdx.x;
  const int wave = tid >> 6, lane = tid & 63;
  const int col = lane & 15, quad = lane >> 4;
  const int n0 = (blockIdx.x * 4 + wave) * 16;

  const f32x4 z4 = {0.f, 0.f, 0.f, 0.f};
  f32x4 acc[6] = {z4, z4, z4, z4, z4, z4};  // 0..3 = KQ o-tiles, 4..5 = V

  const float* xb = x + (size_t)b * C_ * N_ + n0 + col;
  float xcur[8], xnxt[8];
#pragma unroll
  for (int j = 0; j < 8; ++j) xcur[j] = xb[(size_t)(quad * 8 + j) * N_];

#pragma unroll 2
  for (int c0 = 0; c0 < C_; c0 += 32) {
    if (c0 < C_ - 32) {
#pragma unroll
      for (int j = 0; j < 8; ++j)
        xnxt[j] = xb[(size_t)(c0 + 32 + quad * 8 + j) * N_];
    }
    bf16x8 xh, xl;
#pragma unroll
    for (int j = 0; j < 8; ++j) {
      const short h = (short)(__float_as_uint(xcur[j]) >> 16);  // trunc hi
      xh[j] = h;
      xl[j] = f2bf_r(xcur[j] - bf2f(h));
    }
#pragma unroll
    for (int ot = 0; ot < 4; ++ot) {  // K/Q: B-operand = Wt rows 0..63
      const int off = (ot * 16 + col) * C_ + c0 + quad * 8;
      const bf16x8 bh = *(const bf16x8*)(WtHi + off);
      const bf16x8 bl = *(const bf16x8*)(WtLo + off);
      acc[ot] = __builtin_amdgcn_mfma_f32_16x16x32_bf16(xh, bh, acc[ot], 0, 0, 0);
      acc[ot] = __builtin_amdgcn_mfma_f32_16x16x32_bf16(xl, bh, acc[ot], 0, 0, 0);
      acc[ot] = __builtin_amdgcn_mfma_f32_16x16x32_bf16(xh, bl, acc[ot], 0, 0, 0);
    }
#pragma unroll
    for (int ct = 0; ct < 2; ++ct) {  // V: A-operand = Wt rows 64..95
      const int off = ((64 + ct * 16) + col) * C_ + c0 + quad * 8;
      const bf16x8 ah = *(const bf16x8*)(WtHi + off);
      const bf16x8 al = *(const bf16x8*)(WtLo + off);
      acc[4 + ct] = __builtin_amdgcn_mfma_f32_16x16x32_bf16(ah, xh, acc[4 + ct], 0, 0, 0);
      acc[4 + ct] = __builtin_amdgcn_mfma_f32_16x16x32_bf16(ah, xl, acc[4 + ct], 0, 0, 0);
      acc[4 + ct] = __builtin_amdgcn_mfma_f32_16x16x32_bf16(al, xh, acc[4 + ct], 0, 0, 0);
    }
#pragma unroll
    for (int j = 0; j < 8; ++j) xcur[j] = xnxt[j];
  }
  // K/Q epilogue: D[n][o]
#pragma unroll
  for (int ot = 0; ot < 4; ++ot)
#pragma unroll
    for (int r = 0; r < 4; ++r)
      t_tr[((size_t)b * N_ + n0 + quad * 4 + r) * 64 + ot * 16 + col] =
          f2bf(acc[ot][r]);
  // V epilogue: D[c][n]
#pragma unroll
  for (int ct = 0; ct < 2; ++ct)
#pragma unroll
    for (int r = 0; r < 4; ++r)
      Vg[(size_t)b * CR_ * N_ + (size_t)(ct * 16 + quad * 4 + r) * N_ + n0 + col] =
          f2bf(acc[4 + ct][r]);
}

// ---------------------------------------------------------------------------
// Kernel 2: MFMA flash attention, fully decoupled single-wave blocks.
// No max subtraction (p = 2^s is exact-softmax after normalization; scores
// bounded so no overflow).  Grid (128 j-blocks, 4 kv-quarters, 8 b) = 4096
// independent waves.  Wave owns 32 query cols (2 j-tiles) and streams its
// 1024-key quarter in 64-key tiles, kf/vf double-buffered.  No barriers, no
// atomics, no cross-wave anything.  Unnormalized O (bf16) + l (f32) partials
// go to global; out_proj merges the 4 quarters.
// ---------------------------------------------------------------------------
__global__ __launch_bounds__(64, 4) void flash_attn(const short* __restrict__ t_tr,
                                                    const short* __restrict__ Vg,
                                                    short* __restrict__ OPart,
                                                    float* __restrict__ LPart) {
  const int b = blockIdx.z, h = blockIdx.y;
  const int j0 = blockIdx.x * 32;
  const int lane = threadIdx.x;
  const int col = lane & 15, quad = lane >> 4;
  const short* T = t_tr + (size_t)b * N_ * 64;
  const short* V = Vg + (size_t)b * CR_ * N_;

  __shared__ short P[2][1024];  // 4 KB: per-jt region [16 j][64 i], swizzled

  const f32x4 z4 = {0.f, 0.f, 0.f, 0.f};
  bf16x8 qf[2];
#pragma unroll
  for (int jt = 0; jt < 2; ++jt)
    qf[jt] = *(const bf16x8*)(T + (size_t)(j0 + jt * 16 + col) * 64 + 32 + quad * 8);

  f32x4 acc[2][2] = {{z4, z4}, {z4, z4}};
  float ps[2] = {0.f, 0.f};

  const int ibase = h * 1024;
  int i0 = ibase;
  bf16x8 kf[4], vf[4], kfn[4], vfn[4];
#pragma unroll
  for (int it = 0; it < 4; ++it)
    kf[it] = *(const bf16x8*)(T + (size_t)(i0 + it * 16 + col) * 64 + quad * 8);
#pragma unroll
  for (int ct = 0; ct < 2; ++ct)
#pragma unroll
    for (int ks = 0; ks < 2; ++ks)
      vf[ct * 2 + ks] =
          *(const bf16x8*)(V + (size_t)(ct * 16 + col) * N_ + i0 + ks * 32 + quad * 8);

  for (int iter = 0; iter < 16; ++iter) {
    const int inx = ibase + ((iter + 1) & 15) * 64;  // wraps harmlessly at end
#pragma unroll
    for (int it = 0; it < 4; ++it)
      kfn[it] = *(const bf16x8*)(T + (size_t)(inx + it * 16 + col) * 64 + quad * 8);
#pragma unroll
    for (int ct = 0; ct < 2; ++ct)
#pragma unroll
      for (int ks = 0; ks < 2; ++ks)
        vfn[ct * 2 + ks] =
            *(const bf16x8*)(V + (size_t)(ct * 16 + col) * N_ + inx + ks * 32 + quad * 8);

#pragma unroll
    for (int jt = 0; jt < 2; ++jt) {
      f32x4 s[4];
#pragma unroll
      for (int it = 0; it < 4; ++it)
        s[it] = __builtin_amdgcn_mfma_f32_16x16x32_bf16(kf[it], qf[jt], z4, 0, 0, 0);
      // p = exp2(s) raw; accumulate l in f32; pack bf16 to swizzled LDS
      short* Pw = P[jt];
#pragma unroll
      for (int it = 0; it < 4; ++it) {
        const float p0 = __builtin_amdgcn_exp2f(s[it][0]);
        const float p1 = __builtin_amdgcn_exp2f(s[it][1]);
        const float p2 = __builtin_amdgcn_exp2f(s[it][2]);
        const float p3 = __builtin_amdgcn_exp2f(s[it][3]);
        ps[jt] += (p0 + p1) + (p2 + p3);
        bf16x4 pk = {f2bf_r(p0), f2bf_r(p1), f2bf_r(p2), f2bf_r(p3)};
        const int g = it * 2 + (quad >> 1);
        *(bf16x4*)(Pw + col * 64 + ((g ^ (col & 7)) * 8) + (quad & 1) * 4) = pk;
      }
      // O += V @ P
#pragma unroll
      for (int ks = 0; ks < 2; ++ks) {
        const bf16x8 pf =
            *(const bf16x8*)(Pw + col * 64 + (((ks * 4 + quad) ^ (col & 7)) * 8));
        acc[jt][0] = __builtin_amdgcn_mfma_f32_16x16x32_bf16(vf[0 + ks], pf, acc[jt][0], 0, 0, 0);
        acc[jt][1] = __builtin_amdgcn_mfma_f32_16x16x32_bf16(vf[2 + ks], pf, acc[jt][1], 0, 0, 0);
      }
    }
    i0 = inx;
#pragma unroll
    for (int k = 0; k < 4; ++k) { kf[k] = kfn[k]; vf[k] = vfn[k]; }
  }

  // ---- epilogue: l across quads, write O/l partials (no normalization) ----
  const size_t base = ((size_t)b * 4 + h) * N_;
#pragma unroll
  for (int jt = 0; jt < 2; ++jt) {
    float l = ps[jt];
    l += __shfl_xor(l, 16);
    l += __shfl_xor(l, 32);
    if (quad == 0) LPart[base + j0 + jt * 16 + col] = l;
    short* OP = OPart + (base + j0 + jt * 16 + col) * 32;
#pragma unroll
    for (int ct = 0; ct < 2; ++ct) {
      bf16x4 o = {f2bf(acc[jt][ct][0]), f2bf(acc[jt][ct][1]),
                  f2bf(acc[jt][ct][2]), f2bf(acc[jt][ct][3])};
      *(bf16x4*)(OP + ct * 16 + quad * 4) = o;
    }
  }
}

// ---------------------------------------------------------------------------
// Kernel 3: merge 4 KV-quarter partials, normalize, out-proj, residual.
// Grid (64 n-blocks, 2 co-halves, 8 b) = 1024 blocks.
// out[b,co,n] = WoB @ (sum_h O_h / sum_h l_h) + x
// ---------------------------------------------------------------------------
__global__ __launch_bounds__(256) void out_proj(const short* __restrict__ OPart,
                                                const float* __restrict__ LPart,
                                                const short* __restrict__ WoB,
                                                const float* __restrict__ x,
                                                float* __restrict__ out) {
  const int b = blockIdx.z, chalf = blockIdx.y;
  const int tid = threadIdx.x;
  const int wave = tid >> 6, lane = tid & 63;
  const int col = lane & 15, quad = lane >> 4;
  const int jg = blockIdx.x * 64 + wave * 16 + col;  // global n/j
  const int n0 = blockIdx.x * 64 + wave * 16;

  float osum[8];
#pragma unroll
  for (int e = 0; e < 8; ++e) osum[e] = 0.f;
  float lsum = 0.f;
#pragma unroll
  for (int h = 0; h < 4; ++h) {
    const size_t p = ((size_t)b * 4 + h) * N_ + jg;
    const bf16x8 o = *(const bf16x8*)(OPart + p * 32 + quad * 8);
#pragma unroll
    for (int e = 0; e < 8; ++e) osum[e] += bf2f(o[e]);
    lsum += LPart[p];
  }
  const float linv = 1.f / lsum;
  bf16x8 bf;
#pragma unroll
  for (int e = 0; e < 8; ++e) bf[e] = f2bf(osum[e] * linv);

  const f32x4 z4 = {0.f, 0.f, 0.f, 0.f};
  const float* xb = x + (size_t)b * C_ * N_;
  float* ob = out + (size_t)b * C_ * N_;
#pragma unroll
  for (int ct = 0; ct < 8; ++ct) {
    const int ctg = chalf * 8 + ct;
    const bf16x8 af = *(const bf16x8*)(WoB + (ctg * 16 + col) * 32 + quad * 8);
    const f32x4 a = __builtin_amdgcn_mfma_f32_16x16x32_bf16(af, bf, z4, 0, 0, 0);
#pragma unroll
    for (int r = 0; r < 4; ++r) {
      const size_t idx = (size_t)(ctg * 16 + quad * 4 + r) * N_ + n0 + col;
      ob[idx] = a[r] + xb[idx];
    }
  }
}

// ---------------------------------------------------------------------------
extern "C" void kernel_launch(void* const* d_in, const int* in_sizes, int n_in,
                              void* d_out, int out_size, void* d_ws,
                              size_t ws_size, hipStream_t stream) {
  const float* x = (const float*)d_in[0];      // [8,256,64,64]
  const float* Wt = (const float*)d_in[1];     // [96,256]
  const float* Wo = (const float*)d_in[2];     // [256,32]
  const float* scale = (const float*)d_in[3];  // [1]
  float* out = (float*)d_out;

  // ws: OPart bf16 [8][4][4096][32] (8.4 MB) | LPart f32 [8][4][4096] (0.5 MB)
  //   | t_tr bf16 (4.2 MB) | Vg bf16 (2.1 MB) | WtHi | WtLo | WoB  (~15 MB)
  short* OPart = (short*)d_ws;
  float* LPart = (float*)(OPart + (size_t)B_ * 4 * N_ * 32);
  short* t_tr = (short*)(LPart + (size_t)B_ * 4 * N_);
  short* Vg = t_tr + (size_t)B_ * N_ * 64;
  short* WtHi = Vg + (size_t)B_ * CR_ * N_;
  short* WtLo = WtHi + 96 * C_;
  short* WoB = WtLo + 96 * C_;

  prep_weights<<<dim3(128), 256, 0, stream>>>(Wt, Wo, scale, WtHi, WtLo, WoB);
  qkv_mfma<<<dim3(64, B_), 256, 0, stream>>>(x, WtHi, WtLo, t_tr, Vg);
  flash_attn<<<dim3(128, 4, B_), 64, 0, stream>>>(t_tr, Vg, OPart, LPart);
  out_proj<<<dim3(64, 2, B_), 256, 0, stream>>>(OPart, LPart, WoB, x, out);
}

// Round 6
// 157.524 us; speedup vs baseline: 4.5959x; 1.2204x over previous
//
#include <hip/hip_runtime.h>
#include <math.h>

// Problem constants: B=8, C=256, CR=32, N=4096 (=64*64)
#define B_ 8
#define C_ 256
#define CR_ 32
#define N_ 4096

typedef __attribute__((ext_vector_type(8))) short bf16x8;   // MFMA A/B frag
typedef __attribute__((ext_vector_type(4))) short bf16x4;
typedef __attribute__((ext_vector_type(4))) float f32x4;    // 16x16 C/D frag
typedef __attribute__((ext_vector_type(16))) float f32x16;  // 32x32 C/D frag

__device__ inline short f2bf(float f) {  // RTNE
  union { float f; unsigned u; } v; v.f = f;
  unsigned r = v.u + 0x7FFFu + ((v.u >> 16) & 1u);
  return (short)(r >> 16);
}
__device__ inline float bf2f(short h) {
  union { unsigned u; float f; } v; v.u = ((unsigned)(unsigned short)h) << 16;
  return v.f;
}
__device__ inline short f2bf_r(float f) {  // cheap round for hot paths
  return (short)((__float_as_uint(f) + 0x8000u) >> 16);
}

// ---------------------------------------------------------------------------
// Kernel 0: weight prep.  WtHi/WtLo = split-bf16 of Wt (log2e folded into Q
// rows 32..63 so softmax runs in exp2 domain).  WoB = bf16(Wo * scale).
// ---------------------------------------------------------------------------
__global__ __launch_bounds__(256) void prep_weights(const float* __restrict__ Wt,
                                                    const float* __restrict__ Wo,
                                                    const float* __restrict__ scale,
                                                    short* __restrict__ WtHi,
                                                    short* __restrict__ WtLo,
                                                    short* __restrict__ WoB) {
  const int blk = blockIdx.x, tid = threadIdx.x;
  if (blk < 96) {
    float v = Wt[blk * C_ + tid];
    if (blk >= 32 && blk < 64) v *= 1.44269504f;  // log2(e) into Q
    const short h = f2bf(v);
    WtHi[blk * C_ + tid] = h;
    WtLo[blk * C_ + tid] = f2bf(v - bf2f(h));
  } else {
    const int idx = (blk - 96) * 256 + tid;
    WoB[idx] = f2bf(Wo[idx] * scale[0]);
  }
}

// ---------------------------------------------------------------------------
// Kernel 1: QKV projection, pure MFMA, no LDS, x prefetched one chunk ahead.
//   t_tr[b][n][0..31]=K, [32..63]=Q*log2e (bf16);  Vg[b][c][n]=V (bf16)
// ---------------------------------------------------------------------------
__global__ __launch_bounds__(256) void qkv_mfma(const float* __restrict__ x,
                                                const short* __restrict__ WtHi,
                                                const short* __restrict__ WtLo,
                                                short* __restrict__ t_tr,
                                                short* __restrict__ Vg) {
  const int b = blockIdx.y;
  const int tid = threadIdx.x;
  const int wave = tid >> 6, lane = tid & 63;
  const int col = lane & 15, quad = lane >> 4;
  const int n0 = (blockIdx.x * 4 + wave) * 16;

  const f32x4 z4 = {0.f, 0.f, 0.f, 0.f};
  f32x4 acc[6] = {z4, z4, z4, z4, z4, z4};  // 0..3 = KQ o-tiles, 4..5 = V

  const float* xb = x + (size_t)b * C_ * N_ + n0 + col;
  float xcur[8], xnxt[8];
#pragma unroll
  for (int j = 0; j < 8; ++j) xcur[j] = xb[(size_t)(quad * 8 + j) * N_];

#pragma unroll 2
  for (int c0 = 0; c0 < C_; c0 += 32) {
    if (c0 < C_ - 32) {
#pragma unroll
      for (int j = 0; j < 8; ++j)
        xnxt[j] = xb[(size_t)(c0 + 32 + quad * 8 + j) * N_];
    }
    bf16x8 xh, xl;
#pragma unroll
    for (int j = 0; j < 8; ++j) {
      const short h = (short)(__float_as_uint(xcur[j]) >> 16);  // trunc hi
      xh[j] = h;
      xl[j] = f2bf_r(xcur[j] - bf2f(h));
    }
#pragma unroll
    for (int ot = 0; ot < 4; ++ot) {  // K/Q: B-operand = Wt rows 0..63
      const int off = (ot * 16 + col) * C_ + c0 + quad * 8;
      const bf16x8 bh = *(const bf16x8*)(WtHi + off);
      const bf16x8 bl = *(const bf16x8*)(WtLo + off);
      acc[ot] = __builtin_amdgcn_mfma_f32_16x16x32_bf16(xh, bh, acc[ot], 0, 0, 0);
      acc[ot] = __builtin_amdgcn_mfma_f32_16x16x32_bf16(xl, bh, acc[ot], 0, 0, 0);
      acc[ot] = __builtin_amdgcn_mfma_f32_16x16x32_bf16(xh, bl, acc[ot], 0, 0, 0);
    }
#pragma unroll
    for (int ct = 0; ct < 2; ++ct) {  // V: A-operand = Wt rows 64..95
      const int off = ((64 + ct * 16) + col) * C_ + c0 + quad * 8;
      const bf16x8 ah = *(const bf16x8*)(WtHi + off);
      const bf16x8 al = *(const bf16x8*)(WtLo + off);
      acc[4 + ct] = __builtin_amdgcn_mfma_f32_16x16x32_bf16(ah, xh, acc[4 + ct], 0, 0, 0);
      acc[4 + ct] = __builtin_amdgcn_mfma_f32_16x16x32_bf16(ah, xl, acc[4 + ct], 0, 0, 0);
      acc[4 + ct] = __builtin_amdgcn_mfma_f32_16x16x32_bf16(al, xh, acc[4 + ct], 0, 0, 0);
    }
#pragma unroll
    for (int j = 0; j < 8; ++j) xcur[j] = xnxt[j];
  }
  // K/Q epilogue: D[n][o]
#pragma unroll
  for (int ot = 0; ot < 4; ++ot)
#pragma unroll
    for (int r = 0; r < 4; ++r)
      t_tr[((size_t)b * N_ + n0 + quad * 4 + r) * 64 + ot * 16 + col] =
          f2bf(acc[ot][r]);
  // V epilogue: D[c][n]
#pragma unroll
  for (int ct = 0; ct < 2; ++ct)
#pragma unroll
    for (int r = 0; r < 4; ++r)
      Vg[(size_t)b * CR_ * N_ + (size_t)(ct * 16 + quad * 4 + r) * N_ + n0 + col] =
          f2bf(acc[4 + ct][r]);
}

// ---------------------------------------------------------------------------
// Kernel 2: 32x32-MFMA flash attention, zero LDS, in-register P transform.
// Wave = 64 query cols (2 j-tiles of 32) x one KV-quarter (1024 keys in 16
// tiles of 64).  Grid (64 jb, 4 quarters, 8 b) = 2048 single-wave blocks.
// S = K^T Q via 32x32x16 (A = t_tr[i][c] frags, B = t_tr[j][32+c] frags).
// P transform: C/D rows {(reg&3)+8*(reg>>2)+4*h} -> pack pairs (v_perm) +
// shfl_xor(32) + cndmask gives the PV B-operand with no LDS round-trip.
// l = sum p via VALU tree; no max subtraction (scores bounded, exp2 exact
// softmax after normalization).  Partials (bf16 O, f32 l) -> global; same
// layout as R5 so out_proj is unchanged.
// ---------------------------------------------------------------------------
__global__ __launch_bounds__(64, 2) void flash_attn(const short* __restrict__ t_tr,
                                                    const short* __restrict__ Vg,
                                                    short* __restrict__ OPart,
                                                    float* __restrict__ LPart) {
  const int b = blockIdx.z, hq = blockIdx.y;
  const int j0 = blockIdx.x * 64;
  const int lane = threadIdx.x;
  const int j32 = lane & 31, h32 = lane >> 5;
  const short* T = t_tr + (size_t)b * N_ * 64;
  const short* V = Vg + (size_t)b * CR_ * N_;

  const f32x16 z16 = {0.f};
  // Q B-frags, loop-invariant: qf[jt][chunk]
  bf16x8 qf[2][2];
#pragma unroll
  for (int jt = 0; jt < 2; ++jt)
#pragma unroll
    for (int ch = 0; ch < 2; ++ch)
      qf[jt][ch] = *(const bf16x8*)(T + (size_t)(j0 + jt * 32 + j32) * 64 + 32 +
                                    ch * 16 + h32 * 8);

  f32x16 acc[2] = {z16, z16};
  float ps[2] = {0.f, 0.f};

  const int ibase = hq * 1024;
  bf16x8 kf[4], vf[4], kfn[4], vfn[4];  // kf[itile*2+chunk], vf[ich]
#pragma unroll
  for (int it = 0; it < 2; ++it)
#pragma unroll
    for (int ch = 0; ch < 2; ++ch)
      kf[it * 2 + ch] = *(const bf16x8*)(T + (size_t)(ibase + it * 32 + j32) * 64 +
                                         ch * 16 + h32 * 8);
#pragma unroll
  for (int ich = 0; ich < 4; ++ich)
    vf[ich] = *(const bf16x8*)(V + (size_t)j32 * N_ + ibase + ich * 16 + h32 * 8);

  for (int iter = 0; iter < 16; ++iter) {
    const int inx = ibase + ((iter + 1) & 15) * 64;  // wraps harmlessly at end
#pragma unroll
    for (int it = 0; it < 2; ++it)
#pragma unroll
      for (int ch = 0; ch < 2; ++ch)
        kfn[it * 2 + ch] = *(const bf16x8*)(T + (size_t)(inx + it * 32 + j32) * 64 +
                                            ch * 16 + h32 * 8);
#pragma unroll
    for (int ich = 0; ich < 4; ++ich)
      vfn[ich] = *(const bf16x8*)(V + (size_t)j32 * N_ + inx + ich * 16 + h32 * 8);

#pragma unroll
    for (int it = 0; it < 2; ++it) {
#pragma unroll
      for (int jt = 0; jt < 2; ++jt) {
        // ---- S tile (32 i x 32 j), k=32 over two chunks ----
        f32x16 s = __builtin_amdgcn_mfma_f32_32x32x16_bf16(kf[it * 2 + 0], qf[jt][0], z16, 0, 0, 0);
        s = __builtin_amdgcn_mfma_f32_32x32x16_bf16(kf[it * 2 + 1], qf[jt][1], s, 0, 0, 0);
        // ---- p = exp2(s); l tree; pack row-pairs into dwords ----
        float p[16];
#pragma unroll
        for (int r = 0; r < 16; ++r) p[r] = __builtin_amdgcn_exp2f(s[r]);
        ps[jt] += (((p[0] + p[1]) + (p[2] + p[3])) + ((p[4] + p[5]) + (p[6] + p[7]))) +
                  (((p[8] + p[9]) + (p[10] + p[11])) + ((p[12] + p[13]) + (p[14] + p[15])));
        unsigned d[8], xw[8];
#pragma unroll
        for (int k = 0; k < 8; ++k) {
          const unsigned u0 = __float_as_uint(p[2 * k]) + 0x8000u;
          const unsigned u1 = __float_as_uint(p[2 * k + 1]) + 0x8000u;
          d[k] = __builtin_amdgcn_perm(u1, u0, 0x07060302u);  // (bf16 odd)<<16 | bf16 even
        }
#pragma unroll
        for (int k = 0; k < 8; ++k) xw[k] = __shfl_xor((int)d[k], 32);
        // ---- B-frags for PV: rows [8*h32, 8*h32+8) of each 16-row chunk ----
        union { unsigned u[4]; bf16x8 v; } f0, f1;
        f0.u[0] = h32 ? xw[2] : d[0];
        f0.u[1] = h32 ? xw[3] : d[1];
        f0.u[2] = h32 ? d[2] : xw[0];
        f0.u[3] = h32 ? d[3] : xw[1];
        f1.u[0] = h32 ? xw[6] : d[4];
        f1.u[1] = h32 ? xw[7] : d[5];
        f1.u[2] = h32 ? d[6] : xw[4];
        f1.u[3] = h32 ? d[7] : xw[5];
        // ---- O += V @ P ----
        acc[jt] = __builtin_amdgcn_mfma_f32_32x32x16_bf16(vf[it * 2 + 0], f0.v, acc[jt], 0, 0, 0);
        acc[jt] = __builtin_amdgcn_mfma_f32_32x32x16_bf16(vf[it * 2 + 1], f1.v, acc[jt], 0, 0, 0);
      }
    }
#pragma unroll
    for (int k = 0; k < 4; ++k) { kf[k] = kfn[k]; vf[k] = vfn[k]; }
  }

  // ---- epilogue: finish l across halves, write O/l partials ----
  const size_t base = ((size_t)b * 4 + hq) * N_;
#pragma unroll
  for (int jt = 0; jt < 2; ++jt) {
    const float l = ps[jt] + __shfl_xor(ps[jt], 32);
    const int jg = j0 + jt * 32 + j32;
    if (h32 == 0) LPart[base + jg] = l;
    short* OP = OPart + (base + jg) * 32;
#pragma unroll
    for (int g = 0; g < 4; ++g) {  // regs 4g..4g+3 -> c = 8g + 4*h32 + 0..3
      bf16x4 o = {f2bf(acc[jt][4 * g + 0]), f2bf(acc[jt][4 * g + 1]),
                  f2bf(acc[jt][4 * g + 2]), f2bf(acc[jt][4 * g + 3])};
      *(bf16x4*)(OP + 8 * g + 4 * h32) = o;
    }
  }
}

// ---------------------------------------------------------------------------
// Kernel 3: merge 4 KV-quarter partials, normalize, out-proj, residual.
// Grid (64 n-blocks, 2 co-halves, 8 b) = 1024 blocks.
// out[b,co,n] = WoB @ (sum_h O_h / sum_h l_h) + x
// ---------------------------------------------------------------------------
__global__ __launch_bounds__(256) void out_proj(const short* __restrict__ OPart,
                                                const float* __restrict__ LPart,
                                                const short* __restrict__ WoB,
                                                const float* __restrict__ x,
                                                float* __restrict__ out) {
  const int b = blockIdx.z, chalf = blockIdx.y;
  const int tid = threadIdx.x;
  const int wave = tid >> 6, lane = tid & 63;
  const int col = lane & 15, quad = lane >> 4;
  const int jg = blockIdx.x * 64 + wave * 16 + col;  // global n/j
  const int n0 = blockIdx.x * 64 + wave * 16;

  float osum[8];
#pragma unroll
  for (int e = 0; e < 8; ++e) osum[e] = 0.f;
  float lsum = 0.f;
#pragma unroll
  for (int h = 0; h < 4; ++h) {
    const size_t p = ((size_t)b * 4 + h) * N_ + jg;
    const bf16x8 o = *(const bf16x8*)(OPart + p * 32 + quad * 8);
#pragma unroll
    for (int e = 0; e < 8; ++e) osum[e] += bf2f(o[e]);
    lsum += LPart[p];
  }
  const float linv = 1.f / lsum;
  bf16x8 bf;
#pragma unroll
  for (int e = 0; e < 8; ++e) bf[e] = f2bf(osum[e] * linv);

  const f32x4 z4 = {0.f, 0.f, 0.f, 0.f};
  const float* xb = x + (size_t)b * C_ * N_;
  float* ob = out + (size_t)b * C_ * N_;
#pragma unroll
  for (int ct = 0; ct < 8; ++ct) {
    const int ctg = chalf * 8 + ct;
    const bf16x8 af = *(const bf16x8*)(WoB + (ctg * 16 + col) * 32 + quad * 8);
    const f32x4 a = __builtin_amdgcn_mfma_f32_16x16x32_bf16(af, bf, z4, 0, 0, 0);
#pragma unroll
    for (int r = 0; r < 4; ++r) {
      const size_t idx = (size_t)(ctg * 16 + quad * 4 + r) * N_ + n0 + col;
      ob[idx] = a[r] + xb[idx];
    }
  }
}

// ---------------------------------------------------------------------------
extern "C" void kernel_launch(void* const* d_in, const int* in_sizes, int n_in,
                              void* d_out, int out_size, void* d_ws,
                              size_t ws_size, hipStream_t stream) {
  const float* x = (const float*)d_in[0];      // [8,256,64,64]
  const float* Wt = (const float*)d_in[1];     // [96,256]
  const float* Wo = (const float*)d_in[2];     // [256,32]
  const float* scale = (const float*)d_in[3];  // [1]
  float* out = (float*)d_out;

  // ws: OPart bf16 [8][4][4096][32] (8.4 MB) | LPart f32 [8][4][4096] (0.5 MB)
  //   | t_tr bf16 (4.2 MB) | Vg bf16 (2.1 MB) | WtHi | WtLo | WoB  (~15 MB)
  short* OPart = (short*)d_ws;
  float* LPart = (float*)(OPart + (size_t)B_ * 4 * N_ * 32);
  short* t_tr = (short*)(LPart + (size_t)B_ * 4 * N_);
  short* Vg = t_tr + (size_t)B_ * N_ * 64;
  short* WtHi = Vg + (size_t)B_ * CR_ * N_;
  short* WtLo = WtHi + 96 * C_;
  short* WoB = WtLo + 96 * C_;

  prep_weights<<<dim3(128), 256, 0, stream>>>(Wt, Wo, scale, WtHi, WtLo, WoB);
  qkv_mfma<<<dim3(64, B_), 256, 0, stream>>>(x, WtHi, WtLo, t_tr, Vg);
  flash_attn<<<dim3(64, 4, B_), 64, 0, stream>>>(t_tr, Vg, OPart, LPart);
  out_proj<<<dim3(64, 2, B_), 256, 0, stream>>>(OPart, LPart, WoB, x, out);
}